// Round 1
// baseline (750.728 us; speedup 1.0000x reference)
//
#include <hip/hip_runtime.h>
#include <math.h>

#define B 8
#define C 192
#define HW 16384
#define HEADS 4

// ---------------------------------------------------------------------------
// K1: partial Gram  part[b][chunk] = X[:, chunk] X[:, chunk]^T   (192x192)
// grid (chunks, B), block 256 = 16x16 threads, 12x12 register tile
// ---------------------------------------------------------------------------
__global__ __launch_bounds__(256, 2) void k_gram(const float* __restrict__ x,
                                                 float* __restrict__ part,
                                                 int chunks, int chunk_n) {
    __shared__ float xs[C * 65];   // 49,920 B; stride 65 -> bank (c+n)%32
    const int b = blockIdx.y, chunk = blockIdx.x;
    const int t = threadIdx.x;
    const int ti = t >> 4, tj = t & 15;

    float acc[12][12];
#pragma unroll
    for (int i = 0; i < 12; ++i)
#pragma unroll
        for (int j = 0; j < 12; ++j) acc[i][j] = 0.f;

    const float* xb = x + (size_t)b * C * HW + (size_t)chunk * chunk_n;
    const int tiles = chunk_n >> 6;

    for (int tile = 0; tile < tiles; ++tile) {
        __syncthreads();
        const float* src = xb + tile * 64;
#pragma unroll
        for (int r = 0; r < 12; ++r) {              // 3072 float4 loads
            int flat4 = r * 256 + t;
            int c  = flat4 >> 4;
            int n4 = (flat4 & 15) << 2;
            float4 v = *reinterpret_cast<const float4*>(src + (size_t)c * HW + n4);
            float* dst = &xs[c * 65 + n4];
            dst[0] = v.x; dst[1] = v.y; dst[2] = v.z; dst[3] = v.w;
        }
        __syncthreads();
#pragma unroll 4
        for (int n = 0; n < 64; ++n) {
            float a[12], bb[12];
#pragma unroll
            for (int i = 0; i < 12; ++i) a[i] = xs[(ti * 12 + i) * 65 + n];
#pragma unroll
            for (int j = 0; j < 12; ++j) bb[j] = xs[(tj * 12 + j) * 65 + n];
#pragma unroll
            for (int i = 0; i < 12; ++i)
#pragma unroll
                for (int j = 0; j < 12; ++j)
                    acc[i][j] = fmaf(a[i], bb[j], acc[i][j]);
        }
    }

    float* outp = part + ((size_t)b * chunks + chunk) * (C * C);
#pragma unroll
    for (int i = 0; i < 12; ++i)
#pragma unroll
        for (int j = 0; j < 12; ++j)
            outp[(size_t)(ti * 12 + i) * C + tj * 12 + j] = acc[i][j];
}

// ---------------------------------------------------------------------------
// K1r: S[b] = sum_chunk part[b][chunk]
// ---------------------------------------------------------------------------
__global__ void k_reduce(const float* __restrict__ part, float* __restrict__ S,
                         int chunks) {
    int idx = blockIdx.x * 256 + threadIdx.x;   // 294912 total
    int b  = idx / (C * C);
    int cd = idx % (C * C);
    const float* p = part + ((size_t)b * chunks) * (C * C) + cd;
    float s = 0.f;
    for (int j = 0; j < chunks; ++j) s += p[(size_t)j * (C * C)];
    S[idx] = s;
}

// ---------------------------------------------------------------------------
// K2a: U = S Wk^T, Uq = S Wq^T   (per batch, 192x192 each)
// grid (144, B): 12x12 tiles of 16x16
// ---------------------------------------------------------------------------
__global__ void k_uuq(const float* __restrict__ S, const float* __restrict__ Wqkv,
                      float* __restrict__ U, float* __restrict__ Uq) {
    __shared__ float Ss[16 * 193], Wks[16 * 193], Wqs[16 * 193];
    const int b = blockIdx.y;
    const int e0 = (blockIdx.x / 12) * 16, d0 = (blockIdx.x % 12) * 16;
    const int t = threadIdx.x;
    const float* Sb = S + (size_t)b * C * C;
#pragma unroll
    for (int r = 0; r < 12; ++r) {     // 3072 floats each
        int flat = r * 256 + t;
        int row = flat / C, col = flat % C;
        Ss[row * 193 + col]  = Sb[(size_t)(e0 + row) * C + col];
        Wks[row * 193 + col] = Wqkv[(size_t)(C + d0 + row) * C + col];
        Wqs[row * 193 + col] = Wqkv[(size_t)(d0 + row) * C + col];
    }
    __syncthreads();
    const int te = t >> 4, td = t & 15;
    float u = 0.f, uq = 0.f;
#pragma unroll 4
    for (int f = 0; f < C; ++f) {
        float sv = Ss[te * 193 + f];
        u  = fmaf(sv, Wks[td * 193 + f], u);
        uq = fmaf(sv, Wqs[td * 193 + f], uq);
    }
    size_t o = ((size_t)b * C + e0 + te) * C + d0 + td;
    U[o] = u;
    Uq[o] = uq;
}

// ---------------------------------------------------------------------------
// K2b: logits G = Wq_h S Wk_h^T via U; norms; softmax -> attn[b][h][48][48]
// grid (HEADS, B)
// ---------------------------------------------------------------------------
__global__ void k_attn(const float* __restrict__ U, const float* __restrict__ Uq,
                       const float* __restrict__ Wqkv, const float* __restrict__ temp,
                       float* __restrict__ attn) {
    __shared__ float Ub[C * 48];    // 36 KB
    __shared__ float G[48 * 48];
    __shared__ float kn[48], qn[48];
    const int b = blockIdx.y, h = blockIdx.x, t = threadIdx.x;

    const float* Uball = U + (size_t)b * C * C;
#pragma unroll
    for (int r = 0; r < 36; ++r) {           // 9216 floats
        int flat = r * 256 + t;
        int e = flat / 48, dd = flat % 48;
        Ub[flat] = Uball[(size_t)e * C + h * 48 + dd];
    }
    __syncthreads();

    for (int k = 0; k < 9; ++k) {
        int o = k * 256 + t;
        if (o < 2304) {
            int c = o / 48, d = o % 48;
            const float* wq = Wqkv + (size_t)(h * 48 + c) * C;
            float g = 0.f;
#pragma unroll 4
            for (int e = 0; e < C; ++e) g = fmaf(wq[e], Ub[e * 48 + d], g);
            G[o] = g;
        }
    }
    if (t < 48) {
        const float* wk = Wqkv + (size_t)(C + h * 48 + t) * C;
        float s = 0.f;
        for (int e = 0; e < C; ++e) s = fmaf(wk[e], Ub[e * 48 + t], s);
        kn[t] = fmaxf(sqrtf(fmaxf(s, 0.f)), 1e-12f);
    }
    __syncthreads();

    const float* Uqall = Uq + (size_t)b * C * C;
#pragma unroll
    for (int r = 0; r < 36; ++r) {
        int flat = r * 256 + t;
        int e = flat / 48, cc = flat % 48;
        Ub[flat] = Uqall[(size_t)e * C + h * 48 + cc];
    }
    __syncthreads();
    if (t < 48) {
        const float* wq = Wqkv + (size_t)(h * 48 + t) * C;
        float s = 0.f;
        for (int e = 0; e < C; ++e) s = fmaf(wq[e], Ub[e * 48 + t], s);
        qn[t] = fmaxf(sqrtf(fmaxf(s, 0.f)), 1e-12f);
    }
    __syncthreads();

    if (t < 48) {
        int c = t;
        float scale = temp[h] / qn[c];
        float m = -1e30f;
        for (int d = 0; d < 48; ++d) {
            float l = G[c * 48 + d] * scale / kn[d];
            G[c * 48 + d] = l;
            m = fmaxf(m, l);
        }
        float sum = 0.f;
        for (int d = 0; d < 48; ++d) {
            float p = expf(G[c * 48 + d] - m);
            G[c * 48 + d] = p;
            sum += p;
        }
        float inv = 1.f / sum;
        float* arow = attn + (((size_t)b * HEADS + h) * 48 + c) * 48;
        for (int d = 0; d < 48; ++d) arow[d] = G[c * 48 + d] * inv;
    }
}

// ---------------------------------------------------------------------------
// K2c: M = W_out blockdiag(attn);  P = M Wv    (per batch)
// grid (8, B): o-tiles of 24
// ---------------------------------------------------------------------------
__global__ void k_mp(const float* __restrict__ attn, const float* __restrict__ Wout,
                     const float* __restrict__ Wqkv, float* __restrict__ P) {
    __shared__ float As[HEADS * 48 * 48];   // 9216 floats
    __shared__ float Ms[24 * 192];          // 4608 floats
    const int b = blockIdx.y, o0 = blockIdx.x * 24, t = threadIdx.x;
    const float* ab = attn + (size_t)b * HEADS * 48 * 48;
#pragma unroll
    for (int r = 0; r < 36; ++r) As[r * 256 + t] = ab[r * 256 + t];
    __syncthreads();

#pragma unroll
    for (int k = 0; k < 18; ++k) {
        int o = k * 256 + t;                // 4608
        int oo = o / 192, dg = o % 192;
        int h = dg / 48, d = dg % 48;
        const float* wo = Wout + (size_t)(o0 + oo) * C + h * 48;
        const float* ah = As + (h * 48) * 48 + d;
        float m = 0.f;
#pragma unroll 4
        for (int c2 = 0; c2 < 48; ++c2) m = fmaf(wo[c2], ah[c2 * 48], m);
        Ms[o] = m;
    }
    __syncthreads();

#pragma unroll
    for (int k = 0; k < 18; ++k) {
        int o = k * 256 + t;
        int oo = o / 192, e = o % 192;
        float p = 0.f;
#pragma unroll 4
        for (int dg = 0; dg < 192; ++dg)
            p = fmaf(Ms[oo * 192 + dg], Wqkv[(size_t)(2 * C + dg) * C + e], p);
        P[((size_t)b * C + o0 + oo) * C + e] = p;
    }
}

// ---------------------------------------------------------------------------
// K3: out[b] = P[b] @ X[b]    [192x192]@[192x16384]
// grid (128, B), block 256 = 16x16, thread tile 12 o x 8 n, k-chunks of 32
// ---------------------------------------------------------------------------
__global__ __launch_bounds__(256) void k_out(const float* __restrict__ x,
                                             const float* __restrict__ P,
                                             float* __restrict__ out) {
    __shared__ float xs[32 * 132];   // 16.9 KB
    __shared__ float ps[32 * 193];   // 24.7 KB
    const int b = blockIdx.y;
    const int n0 = blockIdx.x * 128;
    const int t = threadIdx.x;
    const int ti = t >> 4, tj = t & 15;

    float acc[12][8];
#pragma unroll
    for (int i = 0; i < 12; ++i)
#pragma unroll
        for (int u = 0; u < 8; ++u) acc[i][u] = 0.f;

    const float* xb = x + (size_t)b * C * HW + n0;
    const float* Pb = P + (size_t)b * C * C;

    for (int e0 = 0; e0 < C; e0 += 32) {
        __syncthreads();
#pragma unroll
        for (int r = 0; r < 4; ++r) {          // xs: 32 x 128
            int flat4 = r * 256 + t;
            int ec = flat4 >> 5;
            int nn4 = (flat4 & 31) << 2;
            float4 v = *reinterpret_cast<const float4*>(xb + (size_t)(e0 + ec) * HW + nn4);
            *reinterpret_cast<float4*>(&xs[ec * 132 + nn4]) = v;
        }
#pragma unroll
        for (int r = 0; r < 24; ++r) {         // ps: 32 e x 192 o (transposed)
            int flat = r * 256 + t;
            int ec = flat & 31, o = flat >> 5;
            ps[ec * 193 + o] = Pb[(size_t)o * C + e0 + ec];
        }
        __syncthreads();
#pragma unroll 4
        for (int ec = 0; ec < 32; ++ec) {
            float xv[8], pv[12];
            float4 v0 = *reinterpret_cast<const float4*>(&xs[ec * 132 + tj * 8]);
            float4 v1 = *reinterpret_cast<const float4*>(&xs[ec * 132 + tj * 8 + 4]);
            xv[0] = v0.x; xv[1] = v0.y; xv[2] = v0.z; xv[3] = v0.w;
            xv[4] = v1.x; xv[5] = v1.y; xv[6] = v1.z; xv[7] = v1.w;
#pragma unroll
            for (int i = 0; i < 12; ++i) pv[i] = ps[ec * 193 + ti * 12 + i];
#pragma unroll
            for (int i = 0; i < 12; ++i)
#pragma unroll
                for (int u = 0; u < 8; ++u)
                    acc[i][u] = fmaf(pv[i], xv[u], acc[i][u]);
        }
    }

    float* ob = out + (size_t)b * C * HW + n0;
#pragma unroll
    for (int i = 0; i < 12; ++i) {
        float4 w0, w1;
        w0.x = acc[i][0]; w0.y = acc[i][1]; w0.z = acc[i][2]; w0.w = acc[i][3];
        w1.x = acc[i][4]; w1.y = acc[i][5]; w1.z = acc[i][6]; w1.w = acc[i][7];
        float* dst = ob + (size_t)(ti * 12 + i) * HW + tj * 8;
        *reinterpret_cast<float4*>(dst) = w0;
        *reinterpret_cast<float4*>(dst + 4) = w1;
    }
}

// ---------------------------------------------------------------------------
extern "C" void kernel_launch(void* const* d_in, const int* in_sizes, int n_in,
                              void* d_out, int out_size, void* d_ws, size_t ws_size,
                              hipStream_t stream) {
    const float* x    = (const float*)d_in[0];
    const float* Wqkv = (const float*)d_in[1];
    const float* Wout = (const float*)d_in[2];
    const float* temp = (const float*)d_in[3];
    float* out = (float*)d_out;
    float* ws  = (float*)d_ws;

    float* S    = ws;                 // 294912
    float* U    = ws + 294912;        // 294912
    float* Uq   = ws + 589824;        // 294912
    float* attn = ws + 884736;        // 73728
    float* P    = ws + 958464;        // 294912
    float* part = ws + 1253376;       // B * chunks * 36864

    int chunks = 64;
    while (chunks > 1 &&
           (1253376ull + (unsigned long long)B * chunks * 36864ull) * 4ull > ws_size)
        chunks >>= 1;
    int chunk_n = HW / chunks;

    k_gram<<<dim3(chunks, B), 256, 0, stream>>>(x, part, chunks, chunk_n);
    k_reduce<<<dim3(1152), 256, 0, stream>>>(part, S, chunks);
    k_uuq<<<dim3(144, B), 256, 0, stream>>>(S, Wqkv, U, Uq);
    k_attn<<<dim3(HEADS, B), 256, 0, stream>>>(U, Uq, Wqkv, temp, attn);
    k_mp<<<dim3(8, B), 256, 0, stream>>>(attn, Wout, Wqkv, P);
    k_out<<<dim3(128, B), 256, 0, stream>>>(x, P, out);
}

// Round 3
// 686.886 us; speedup vs baseline: 1.0929x; 1.0929x over previous
//
#include <hip/hip_runtime.h>
#include <math.h>

#define B 8
#define C 192
#define HW 16384
#define HEADS 4

typedef __attribute__((ext_vector_type(8)))  short short8;
typedef __attribute__((ext_vector_type(16))) float f32x16;

typedef unsigned short ushortT;
typedef unsigned int   uintT;

__device__ __forceinline__ ushortT f2bf(float f) {
    uintT u = __float_as_uint(f);
    u = (u + 0x7FFFu + ((u >> 16) & 1u)) >> 16;
    return (ushortT)u;
}
__device__ __forceinline__ float bf2f(ushortT h) {
    return __uint_as_float(((uintT)h) << 16);
}

// ---------------------------------------------------------------------------
// K1: partial Gram  part[b][chunk] = X[:, chunk] X[:, chunk]^T   (192x192)
// ROUND-1 PROVEN VERSION (fp32 VALU, 12x12 register tile).
// ---------------------------------------------------------------------------
__global__ __launch_bounds__(256, 2) void k_gram(const float* __restrict__ x,
                                                 float* __restrict__ part,
                                                 int chunks, int chunk_n) {
    __shared__ float xs[C * 65];   // 49,920 B; stride 65 -> bank (c+n)%32
    const int b = blockIdx.y, chunk = blockIdx.x;
    const int t = threadIdx.x;
    const int ti = t >> 4, tj = t & 15;

    float acc[12][12];
#pragma unroll
    for (int i = 0; i < 12; ++i)
#pragma unroll
        for (int j = 0; j < 12; ++j) acc[i][j] = 0.f;

    const float* xb = x + (size_t)b * C * HW + (size_t)chunk * chunk_n;
    const int tiles = chunk_n >> 6;

    for (int tile = 0; tile < tiles; ++tile) {
        __syncthreads();
        const float* src = xb + tile * 64;
#pragma unroll
        for (int r = 0; r < 12; ++r) {              // 3072 float4 loads
            int flat4 = r * 256 + t;
            int c  = flat4 >> 4;
            int n4 = (flat4 & 15) << 2;
            float4 v = *reinterpret_cast<const float4*>(src + (size_t)c * HW + n4);
            float* dst = &xs[c * 65 + n4];
            dst[0] = v.x; dst[1] = v.y; dst[2] = v.z; dst[3] = v.w;
        }
        __syncthreads();
#pragma unroll 4
        for (int n = 0; n < 64; ++n) {
            float a[12], bb[12];
#pragma unroll
            for (int i = 0; i < 12; ++i) a[i] = xs[(ti * 12 + i) * 65 + n];
#pragma unroll
            for (int j = 0; j < 12; ++j) bb[j] = xs[(tj * 12 + j) * 65 + n];
#pragma unroll
            for (int i = 0; i < 12; ++i)
#pragma unroll
                for (int j = 0; j < 12; ++j)
                    acc[i][j] = fmaf(a[i], bb[j], acc[i][j]);
        }
    }

    float* outp = part + ((size_t)b * chunks + chunk) * (C * C);
#pragma unroll
    for (int i = 0; i < 12; ++i)
#pragma unroll
        for (int j = 0; j < 12; ++j)
            outp[(size_t)(ti * 12 + i) * C + tj * 12 + j] = acc[i][j];
}

// ---------------------------------------------------------------------------
// K1r: S[b] = sum_chunk part[b][chunk]
// ---------------------------------------------------------------------------
__global__ void k_reduce(const float* __restrict__ part, float* __restrict__ S,
                         int chunks) {
    int idx = blockIdx.x * 256 + threadIdx.x;   // 294912 total
    int b  = idx / (C * C);
    int cd = idx % (C * C);
    const float* p = part + ((size_t)b * chunks) * (C * C) + cd;
    float s = 0.f;
    for (int j = 0; j < chunks; ++j) s += p[(size_t)j * (C * C)];
    S[idx] = s;
}

// ---------------------------------------------------------------------------
// K2a: U = S Wk^T, Uq = S Wq^T   (per batch, 192x192 each)
// ---------------------------------------------------------------------------
__global__ void k_uuq(const float* __restrict__ S, const float* __restrict__ Wqkv,
                      float* __restrict__ U, float* __restrict__ Uq) {
    __shared__ float Ss[16 * 193], Wks[16 * 193], Wqs[16 * 193];
    const int b = blockIdx.y;
    const int e0 = (blockIdx.x / 12) * 16, d0 = (blockIdx.x % 12) * 16;
    const int t = threadIdx.x;
    const float* Sb = S + (size_t)b * C * C;
#pragma unroll
    for (int r = 0; r < 12; ++r) {
        int flat = r * 256 + t;
        int row = flat / C, col = flat % C;
        Ss[row * 193 + col]  = Sb[(size_t)(e0 + row) * C + col];
        Wks[row * 193 + col] = Wqkv[(size_t)(C + d0 + row) * C + col];
        Wqs[row * 193 + col] = Wqkv[(size_t)(d0 + row) * C + col];
    }
    __syncthreads();
    const int te = t >> 4, td = t & 15;
    float u = 0.f, uq = 0.f;
#pragma unroll 4
    for (int f = 0; f < C; ++f) {
        float sv = Ss[te * 193 + f];
        u  = fmaf(sv, Wks[td * 193 + f], u);
        uq = fmaf(sv, Wqs[td * 193 + f], uq);
    }
    size_t o = ((size_t)b * C + e0 + te) * C + d0 + td;
    U[o] = u;
    Uq[o] = uq;
}

// ---------------------------------------------------------------------------
// K2b: logits, norms, softmax -> attn[b][h][48][48]
// ---------------------------------------------------------------------------
__global__ void k_attn(const float* __restrict__ U, const float* __restrict__ Uq,
                       const float* __restrict__ Wqkv, const float* __restrict__ temp,
                       float* __restrict__ attn) {
    __shared__ float Ub[C * 48];
    __shared__ float G[48 * 48];
    __shared__ float kn[48], qn[48];
    const int b = blockIdx.y, h = blockIdx.x, t = threadIdx.x;

    const float* Uball = U + (size_t)b * C * C;
#pragma unroll
    for (int r = 0; r < 36; ++r) {
        int flat = r * 256 + t;
        int e = flat / 48, dd = flat % 48;
        Ub[flat] = Uball[(size_t)e * C + h * 48 + dd];
    }
    __syncthreads();

    for (int k = 0; k < 9; ++k) {
        int o = k * 256 + t;
        if (o < 2304) {
            int c = o / 48, d = o % 48;
            const float* wq = Wqkv + (size_t)(h * 48 + c) * C;
            float g = 0.f;
#pragma unroll 4
            for (int e = 0; e < C; ++e) g = fmaf(wq[e], Ub[e * 48 + d], g);
            G[o] = g;
        }
    }
    if (t < 48) {
        const float* wk = Wqkv + (size_t)(C + h * 48 + t) * C;
        float s = 0.f;
        for (int e = 0; e < C; ++e) s = fmaf(wk[e], Ub[e * 48 + t], s);
        kn[t] = fmaxf(sqrtf(fmaxf(s, 0.f)), 1e-12f);
    }
    __syncthreads();

    const float* Uqall = Uq + (size_t)b * C * C;
#pragma unroll
    for (int r = 0; r < 36; ++r) {
        int flat = r * 256 + t;
        int e = flat / 48, cc = flat % 48;
        Ub[flat] = Uqall[(size_t)e * C + h * 48 + cc];
    }
    __syncthreads();
    if (t < 48) {
        const float* wq = Wqkv + (size_t)(h * 48 + t) * C;
        float s = 0.f;
        for (int e = 0; e < C; ++e) s = fmaf(wq[e], Ub[e * 48 + t], s);
        qn[t] = fmaxf(sqrtf(fmaxf(s, 0.f)), 1e-12f);
    }
    __syncthreads();

    if (t < 48) {
        int c = t;
        float scale = temp[h] / qn[c];
        float m = -1e30f;
        for (int d = 0; d < 48; ++d) {
            float lg = G[c * 48 + d] * scale / kn[d];
            G[c * 48 + d] = lg;
            m = fmaxf(m, lg);
        }
        float sum = 0.f;
        for (int d = 0; d < 48; ++d) {
            float p = expf(G[c * 48 + d] - m);
            G[c * 48 + d] = p;
            sum += p;
        }
        float inv = 1.f / sum;
        float* arow = attn + (((size_t)b * HEADS + h) * 48 + c) * 48;
        for (int d = 0; d < 48; ++d) arow[d] = G[c * 48 + d] * inv;
    }
}

// ---------------------------------------------------------------------------
// K2c: M = W_out blockdiag(attn);  P = M Wv ; emit P as bf16 hi/lo
// ---------------------------------------------------------------------------
__global__ void k_mp(const float* __restrict__ attn, const float* __restrict__ Wout,
                     const float* __restrict__ Wqkv,
                     ushortT* __restrict__ phi, ushortT* __restrict__ plo) {
    __shared__ float As[HEADS * 48 * 48];
    __shared__ float Ms[24 * 192];
    const int b = blockIdx.y, o0 = blockIdx.x * 24, t = threadIdx.x;
    const float* ab = attn + (size_t)b * HEADS * 48 * 48;
#pragma unroll
    for (int r = 0; r < 36; ++r) As[r * 256 + t] = ab[r * 256 + t];
    __syncthreads();

#pragma unroll
    for (int k = 0; k < 18; ++k) {
        int o = k * 256 + t;
        int oo = o / 192, dg = o % 192;
        int h = dg / 48, d = dg % 48;
        const float* wo = Wout + (size_t)(o0 + oo) * C + h * 48;
        const float* ah = As + (h * 48) * 48 + d;
        float m = 0.f;
#pragma unroll 4
        for (int c2 = 0; c2 < 48; ++c2) m = fmaf(wo[c2], ah[c2 * 48], m);
        Ms[o] = m;
    }
    __syncthreads();

#pragma unroll
    for (int k = 0; k < 18; ++k) {
        int o = k * 256 + t;
        int oo = o / 192, e = o % 192;
        float p = 0.f;
#pragma unroll 4
        for (int dg = 0; dg < 192; ++dg)
            p = fmaf(Ms[oo * 192 + dg], Wqkv[(size_t)(2 * C + dg) * C + e], p);
        size_t off = ((size_t)b * C + o0 + oo) * C + e;
        ushortT h16 = f2bf(p);
        phi[off] = h16;
        plo[off] = f2bf(p - bf2f(h16));
    }
}

// ---------------------------------------------------------------------------
// K3: out[b] = P[b] @ X[b] via bf16-split MFMA, no LDS.
// grid (128, B); block = 4 waves; wave = 192 o x 32 n (6 tiles of 32x32).
// ---------------------------------------------------------------------------
__global__ __launch_bounds__(256, 2) void k_out(const float* __restrict__ x,
                                                const ushortT* __restrict__ phi,
                                                const ushortT* __restrict__ plo,
                                                float* __restrict__ out) {
    const int b = blockIdx.y;
    const int t = threadIdx.x;
    const int w = t >> 6, l = t & 63;
    const int lr = l & 31, lh = l >> 5;
    const int n0 = blockIdx.x * 128 + w * 32;

    f32x16 acc[6];
#pragma unroll
    for (int i = 0; i < 6; ++i)
#pragma unroll
        for (int r = 0; r < 16; ++r) acc[i][r] = 0.f;

    const float* xb = x + (size_t)b * C * HW + n0 + lr;
    const ushortT* ph = phi + (size_t)b * C * C;
    const ushortT* pl = plo + (size_t)b * C * C;

#pragma unroll 2
    for (int ks = 0; ks < 12; ++ks) {
        // B-frag: lane holds X[e0 .. e0+7][n0+lr], e0 = ks*16 + lh*8
        float bv[8];
#pragma unroll
        for (int j = 0; j < 8; ++j)
            bv[j] = xb[(size_t)(ks * 16 + lh * 8 + j) * HW];
        short8 bhiF, bloF;
#pragma unroll
        for (int j = 0; j < 8; ++j) {
            ushortT h16 = f2bf(bv[j]);
            bhiF[j] = (short)h16;
            bloF[j] = (short)f2bf(bv[j] - bf2f(h16));
        }
#pragma unroll
        for (int i = 0; i < 6; ++i) {
            int off = (i * 32 + lr) * C + ks * 16 + lh * 8;
            short8 ah = *reinterpret_cast<const short8*>(&ph[off]);
            short8 al = *reinterpret_cast<const short8*>(&pl[off]);
            acc[i] = __builtin_amdgcn_mfma_f32_32x32x16_bf16(ah, bhiF, acc[i], 0, 0, 0);
            acc[i] = __builtin_amdgcn_mfma_f32_32x32x16_bf16(ah, bloF, acc[i], 0, 0, 0);
            acc[i] = __builtin_amdgcn_mfma_f32_32x32x16_bf16(al, bhiF, acc[i], 0, 0, 0);
        }
    }

    float* ob = out + (size_t)b * C * HW + n0 + lr;
#pragma unroll
    for (int i = 0; i < 6; ++i)
#pragma unroll
        for (int r = 0; r < 16; ++r) {
            int row = i * 32 + (r & 3) + 8 * (r >> 2) + 4 * lh;
            ob[(size_t)row * HW] = acc[i][r];
        }
}

// ---------------------------------------------------------------------------
extern "C" void kernel_launch(void* const* d_in, const int* in_sizes, int n_in,
                              void* d_out, int out_size, void* d_ws, size_t ws_size,
                              hipStream_t stream) {
    const float* x    = (const float*)d_in[0];
    const float* Wqkv = (const float*)d_in[1];
    const float* Wout = (const float*)d_in[2];
    const float* temp = (const float*)d_in[3];
    float* out = (float*)d_out;
    float* ws  = (float*)d_ws;

    float*   S    = ws;                         // 294912 f
    float*   U    = ws + 294912;                // 294912 f
    float*   Uq   = ws + 589824;                // 294912 f
    float*   attn = ws + 884736;                // 73728 f
    ushortT* phi  = (ushortT*)(ws + 958464);    // 294912 u16 (147456 f)
    ushortT* plo  = (ushortT*)(ws + 1105920);   // 294912 u16
    float*   part = ws + 1253376;               // B * chunks * 36864 f

    int chunks = 64;
    while (chunks > 1 &&
           (1253376ull + (unsigned long long)B * chunks * 36864ull) * 4ull > ws_size)
        chunks >>= 1;
    int chunk_n = HW / chunks;

    k_gram<<<dim3(chunks, B), 256, 0, stream>>>(x, part, chunks, chunk_n);
    k_reduce<<<dim3(1152), 256, 0, stream>>>(part, S, chunks);
    k_uuq<<<dim3(144, B), 256, 0, stream>>>(S, Wqkv, U, Uq);
    k_attn<<<dim3(HEADS, B), 256, 0, stream>>>(U, Uq, Wqkv, temp, attn);
    k_mp<<<dim3(8, B), 256, 0, stream>>>(attn, Wout, Wqkv, phi, plo);
    k_out<<<dim3(128, B), 256, 0, stream>>>(x, phi, plo, out);
}

// Round 7
// 528.981 us; speedup vs baseline: 1.4192x; 1.2985x over previous
//
#include <hip/hip_runtime.h>
#include <math.h>

#define B 8
#define C 192
#define HW 16384
#define HEADS 4

typedef __attribute__((ext_vector_type(8)))  short short8;
typedef __attribute__((ext_vector_type(16))) float f32x16;

typedef unsigned short ushortT;
typedef unsigned int   uintT;

__device__ __forceinline__ ushortT f2bf(float f) {
    uintT u = __float_as_uint(f);
    u = (u + 0x7FFFu + ((u >> 16) & 1u)) >> 16;
    return (ushortT)u;
}
__device__ __forceinline__ float bf2f(ushortT h) {
    return __uint_as_float(((uintT)h) << 16);
}

// ---------------------------------------------------------------------------
// K1: partial Gram via bf16-split MFMA — CLEAN-ROOM REBUILD.
// part[b][chunk] = X[:,chunk] X[:,chunk]^T  (192x192)
// LDS: [192][64] ushort rows (128 B stride, no pad), XOR-swizzled
// byte ^= (row&7)<<4. Swizzle is a bijection -> write coverage == read
// coverage (the round-2 failure mode, read-of-unwritten-LDS, is impossible).
// 4 waves (2x2), wave tile 96x96 = 3x3 MFMA tiles of 32x32, 3 hi/lo passes.
// ---------------------------------------------------------------------------
__global__ __launch_bounds__(256, 2) void k_gram(const float* __restrict__ x,
                                                 float* __restrict__ part,
                                                 int chunks, int chunk_n) {
    __shared__ ushortT xhi[192 * 64];   // 24576 B
    __shared__ ushortT xlo[192 * 64];   // 24576 B
    const int b = blockIdx.y, chunk = blockIdx.x;
    const int t = threadIdx.x;
    const int w = t >> 6, l = t & 63;
    const int wr = w >> 1, wc = w & 1;      // wave tile origin (rows wr*96, cols wc*96)
    const int lr = l & 31, lh = l >> 5;     // lane row-in-tile, k-half

    f32x16 acc[3][3];
#pragma unroll
    for (int i = 0; i < 3; ++i)
#pragma unroll
        for (int j = 0; j < 3; ++j)
#pragma unroll
            for (int r = 0; r < 16; ++r) acc[i][j][r] = 0.f;

    const float* xb = x + (size_t)b * C * HW + (size_t)chunk * chunk_n;
    char* hbase = reinterpret_cast<char*>(xhi);
    char* lbase = reinterpret_cast<char*>(xlo);

    for (int n0 = 0; n0 < chunk_n; n0 += 64) {
        __syncthreads();
        // stage + split-convert: 192 rows x 64 n, swizzled store
#pragma unroll
        for (int r = 0; r < 12; ++r) {
            int flat = r * 256 + t;
            int c  = flat >> 4;           // 0..191
            int n4 = (flat & 15) << 2;    // 0,4,...,60
            float4 v = *reinterpret_cast<const float4*>(xb + (size_t)c * HW + n0 + n4);
            ushortT h0 = f2bf(v.x), h1 = f2bf(v.y), h2 = f2bf(v.z), h3 = f2bf(v.w);
            ushort4 hv = make_ushort4(h0, h1, h2, h3);
            ushort4 lv = make_ushort4(f2bf(v.x - bf2f(h0)), f2bf(v.y - bf2f(h1)),
                                      f2bf(v.z - bf2f(h2)), f2bf(v.w - bf2f(h3)));
            int byte = ((c << 7) + (n4 << 1)) ^ ((c & 7) << 4);
            *reinterpret_cast<ushort4*>(hbase + byte) = hv;
            *reinterpret_cast<ushort4*>(lbase + byte) = lv;
        }
        __syncthreads();
#pragma unroll
        for (int ks = 0; ks < 4; ++ks) {
            short8 ahi[3], alo[3], bhi[3], blo[3];
            const int kb = (ks * 16 + lh * 8) << 1;   // byte offset of k-slice
#pragma unroll
            for (int i = 0; i < 3; ++i) {
                int ra = wr * 96 + i * 32 + lr;
                int ba = ((ra << 7) + kb) ^ ((ra & 7) << 4);
                ahi[i] = *reinterpret_cast<const short8*>(hbase + ba);
                alo[i] = *reinterpret_cast<const short8*>(lbase + ba);
                int rb = wc * 96 + i * 32 + lr;
                int bbyte = ((rb << 7) + kb) ^ ((rb & 7) << 4);
                bhi[i] = *reinterpret_cast<const short8*>(hbase + bbyte);
                blo[i] = *reinterpret_cast<const short8*>(lbase + bbyte);
            }
#pragma unroll
            for (int i = 0; i < 3; ++i)
#pragma unroll
                for (int j = 0; j < 3; ++j) {
                    acc[i][j] = __builtin_amdgcn_mfma_f32_32x32x16_bf16(ahi[i], bhi[j], acc[i][j], 0, 0, 0);
                    acc[i][j] = __builtin_amdgcn_mfma_f32_32x32x16_bf16(ahi[i], blo[j], acc[i][j], 0, 0, 0);
                    acc[i][j] = __builtin_amdgcn_mfma_f32_32x32x16_bf16(alo[i], bhi[j], acc[i][j], 0, 0, 0);
                }
        }
    }

    float* outp = part + ((size_t)b * chunks + chunk) * (C * C);
#pragma unroll
    for (int i = 0; i < 3; ++i)
#pragma unroll
        for (int j = 0; j < 3; ++j)
#pragma unroll
            for (int r = 0; r < 16; ++r) {
                int row = wr * 96 + i * 32 + (r & 3) + 8 * (r >> 2) + 4 * lh;
                int col = wc * 96 + j * 32 + lr;
                outp[(size_t)row * C + col] = acc[i][j][r];
            }
}

// ---------------------------------------------------------------------------
// K1r: S[b] = sum_chunk part[b][chunk]
// ---------------------------------------------------------------------------
__global__ void k_reduce(const float* __restrict__ part, float* __restrict__ S,
                         int chunks) {
    int idx = blockIdx.x * 256 + threadIdx.x;   // 294912 total
    int b  = idx / (C * C);
    int cd = idx % (C * C);
    const float* p = part + ((size_t)b * chunks) * (C * C) + cd;
    float s = 0.f;
    for (int j = 0; j < chunks; ++j) s += p[(size_t)j * (C * C)];
    S[idx] = s;
}

// ---------------------------------------------------------------------------
// K2a: U = S Wk^T, Uq = S Wq^T   (per batch, 192x192 each)
// ---------------------------------------------------------------------------
__global__ void k_uuq(const float* __restrict__ S, const float* __restrict__ Wqkv,
                      float* __restrict__ U, float* __restrict__ Uq) {
    __shared__ float Ss[16 * 193], Wks[16 * 193], Wqs[16 * 193];
    const int b = blockIdx.y;
    const int e0 = (blockIdx.x / 12) * 16, d0 = (blockIdx.x % 12) * 16;
    const int t = threadIdx.x;
    const float* Sb = S + (size_t)b * C * C;
#pragma unroll
    for (int r = 0; r < 12; ++r) {
        int flat = r * 256 + t;
        int row = flat / C, col = flat % C;
        Ss[row * 193 + col]  = Sb[(size_t)(e0 + row) * C + col];
        Wks[row * 193 + col] = Wqkv[(size_t)(C + d0 + row) * C + col];
        Wqs[row * 193 + col] = Wqkv[(size_t)(d0 + row) * C + col];
    }
    __syncthreads();
    const int te = t >> 4, td = t & 15;
    float u = 0.f, uq = 0.f;
#pragma unroll 4
    for (int f = 0; f < C; ++f) {
        float sv = Ss[te * 193 + f];
        u  = fmaf(sv, Wks[td * 193 + f], u);
        uq = fmaf(sv, Wqs[td * 193 + f], uq);
    }
    size_t o = ((size_t)b * C + e0 + te) * C + d0 + td;
    U[o] = u;
    Uq[o] = uq;
}

// ---------------------------------------------------------------------------
// K2b: logits, norms, softmax -> attn[b][h][48][48]
// ---------------------------------------------------------------------------
__global__ void k_attn(const float* __restrict__ U, const float* __restrict__ Uq,
                       const float* __restrict__ Wqkv, const float* __restrict__ temp,
                       float* __restrict__ attn) {
    __shared__ float Ub[C * 48];
    __shared__ float G[48 * 48];
    __shared__ float kn[48], qn[48];
    const int b = blockIdx.y, h = blockIdx.x, t = threadIdx.x;

    const float* Uball = U + (size_t)b * C * C;
#pragma unroll
    for (int r = 0; r < 36; ++r) {
        int flat = r * 256 + t;
        int e = flat / 48, dd = flat % 48;
        Ub[flat] = Uball[(size_t)e * C + h * 48 + dd];
    }
    __syncthreads();

    for (int k = 0; k < 9; ++k) {
        int o = k * 256 + t;
        if (o < 2304) {
            int c = o / 48, d = o % 48;
            const float* wq = Wqkv + (size_t)(h * 48 + c) * C;
            float g = 0.f;
#pragma unroll 4
            for (int e = 0; e < C; ++e) g = fmaf(wq[e], Ub[e * 48 + d], g);
            G[o] = g;
        }
    }
    if (t < 48) {
        const float* wk = Wqkv + (size_t)(C + h * 48 + t) * C;
        float s = 0.f;
        for (int e = 0; e < C; ++e) s = fmaf(wk[e], Ub[e * 48 + t], s);
        kn[t] = fmaxf(sqrtf(fmaxf(s, 0.f)), 1e-12f);
    }
    __syncthreads();

    const float* Uqall = Uq + (size_t)b * C * C;
#pragma unroll
    for (int r = 0; r < 36; ++r) {
        int flat = r * 256 + t;
        int e = flat / 48, cc = flat % 48;
        Ub[flat] = Uqall[(size_t)e * C + h * 48 + cc];
    }
    __syncthreads();
    if (t < 48) {
        const float* wq = Wqkv + (size_t)(h * 48 + t) * C;
        float s = 0.f;
        for (int e = 0; e < C; ++e) s = fmaf(wq[e], Ub[e * 48 + t], s);
        qn[t] = fmaxf(sqrtf(fmaxf(s, 0.f)), 1e-12f);
    }
    __syncthreads();

    if (t < 48) {
        int c = t;
        float scale = temp[h] / qn[c];
        float m = -1e30f;
        for (int d = 0; d < 48; ++d) {
            float lg = G[c * 48 + d] * scale / kn[d];
            G[c * 48 + d] = lg;
            m = fmaxf(m, lg);
        }
        float sum = 0.f;
        for (int d = 0; d < 48; ++d) {
            float p = expf(G[c * 48 + d] - m);
            G[c * 48 + d] = p;
            sum += p;
        }
        float inv = 1.f / sum;
        float* arow = attn + (((size_t)b * HEADS + h) * 48 + c) * 48;
        for (int d = 0; d < 48; ++d) arow[d] = G[c * 48 + d] * inv;
    }
}

// ---------------------------------------------------------------------------
// K2c: M = W_out blockdiag(attn);  P = M Wv ; emit P as bf16 hi/lo
// ---------------------------------------------------------------------------
__global__ void k_mp(const float* __restrict__ attn, const float* __restrict__ Wout,
                     const float* __restrict__ Wqkv,
                     ushortT* __restrict__ phi, ushortT* __restrict__ plo) {
    __shared__ float As[HEADS * 48 * 48];
    __shared__ float Ms[24 * 192];
    const int b = blockIdx.y, o0 = blockIdx.x * 24, t = threadIdx.x;
    const float* ab = attn + (size_t)b * HEADS * 48 * 48;
#pragma unroll
    for (int r = 0; r < 36; ++r) As[r * 256 + t] = ab[r * 256 + t];
    __syncthreads();

#pragma unroll
    for (int k = 0; k < 18; ++k) {
        int o = k * 256 + t;
        int oo = o / 192, dg = o % 192;
        int h = dg / 48, d = dg % 48;
        const float* wo = Wout + (size_t)(o0 + oo) * C + h * 48;
        const float* ah = As + (h * 48) * 48 + d;
        float m = 0.f;
#pragma unroll 4
        for (int c2 = 0; c2 < 48; ++c2) m = fmaf(wo[c2], ah[c2 * 48], m);
        Ms[o] = m;
    }
    __syncthreads();

#pragma unroll
    for (int k = 0; k < 18; ++k) {
        int o = k * 256 + t;
        int oo = o / 192, e = o % 192;
        float p = 0.f;
#pragma unroll 4
        for (int dg = 0; dg < 192; ++dg)
            p = fmaf(Ms[oo * 192 + dg], Wqkv[(size_t)(2 * C + dg) * C + e], p);
        size_t off = ((size_t)b * C + o0 + oo) * C + e;
        ushortT h16 = f2bf(p);
        phi[off] = h16;
        plo[off] = f2bf(p - bf2f(h16));
    }
}

// ---------------------------------------------------------------------------
// K3: out[b] = P[b] @ X[b] via bf16-split MFMA, no LDS.
// grid (128, B); block = 4 waves; wave = 192 o x 32 n (6 tiles of 32x32).
// ---------------------------------------------------------------------------
__global__ __launch_bounds__(256, 2) void k_out(const float* __restrict__ x,
                                                const ushortT* __restrict__ phi,
                                                const ushortT* __restrict__ plo,
                                                float* __restrict__ out) {
    const int b = blockIdx.y;
    const int t = threadIdx.x;
    const int w = t >> 6, l = t & 63;
    const int lr = l & 31, lh = l >> 5;
    const int n0 = blockIdx.x * 128 + w * 32;

    f32x16 acc[6];
#pragma unroll
    for (int i = 0; i < 6; ++i)
#pragma unroll
        for (int r = 0; r < 16; ++r) acc[i][r] = 0.f;

    const float* xb = x + (size_t)b * C * HW + n0 + lr;
    const ushortT* ph = phi + (size_t)b * C * C;
    const ushortT* pl = plo + (size_t)b * C * C;

#pragma unroll 2
    for (int ks = 0; ks < 12; ++ks) {
        // B-frag: lane holds X[e0 .. e0+7][n0+lr], e0 = ks*16 + lh*8
        float bv[8];
#pragma unroll
        for (int j = 0; j < 8; ++j)
            bv[j] = xb[(size_t)(ks * 16 + lh * 8 + j) * HW];
        short8 bhiF, bloF;
#pragma unroll
        for (int j = 0; j < 8; ++j) {
            ushortT h16 = f2bf(bv[j]);
            bhiF[j] = (short)h16;
            bloF[j] = (short)f2bf(bv[j] - bf2f(h16));
        }
#pragma unroll
        for (int i = 0; i < 6; ++i) {
            int off = (i * 32 + lr) * C + ks * 16 + lh * 8;
            short8 ah = *reinterpret_cast<const short8*>(&ph[off]);
            short8 al = *reinterpret_cast<const short8*>(&pl[off]);
            acc[i] = __builtin_amdgcn_mfma_f32_32x32x16_bf16(ah, bhiF, acc[i], 0, 0, 0);
            acc[i] = __builtin_amdgcn_mfma_f32_32x32x16_bf16(ah, bloF, acc[i], 0, 0, 0);
            acc[i] = __builtin_amdgcn_mfma_f32_32x32x16_bf16(al, bhiF, acc[i], 0, 0, 0);
        }
    }

    float* ob = out + (size_t)b * C * HW + n0 + lr;
#pragma unroll
    for (int i = 0; i < 6; ++i)
#pragma unroll
        for (int r = 0; r < 16; ++r) {
            int row = i * 32 + (r & 3) + 8 * (r >> 2) + 4 * lh;
            ob[(size_t)row * HW] = acc[i][r];
        }
}

// ---------------------------------------------------------------------------
extern "C" void kernel_launch(void* const* d_in, const int* in_sizes, int n_in,
                              void* d_out, int out_size, void* d_ws, size_t ws_size,
                              hipStream_t stream) {
    const float* x    = (const float*)d_in[0];
    const float* Wqkv = (const float*)d_in[1];
    const float* Wout = (const float*)d_in[2];
    const float* temp = (const float*)d_in[3];
    float* out = (float*)d_out;
    float* ws  = (float*)d_ws;

    float*   S    = ws;                         // 294912 f
    float*   U    = ws + 294912;                // 294912 f
    float*   Uq   = ws + 589824;                // 294912 f
    float*   attn = ws + 884736;                // 73728 f
    ushortT* phi  = (ushortT*)(ws + 958464);    // 294912 u16 (147456 f)
    ushortT* plo  = (ushortT*)(ws + 1105920);   // 294912 u16
    float*   part = ws + 1253376;               // B * chunks * 36864 f

    int chunks = 64;
    while (chunks > 1 &&
           (1253376ull + (unsigned long long)B * chunks * 36864ull) * 4ull > ws_size)
        chunks >>= 1;
    int chunk_n = HW / chunks;

    k_gram<<<dim3(chunks, B), 256, 0, stream>>>(x, part, chunks, chunk_n);
    k_reduce<<<dim3(1152), 256, 0, stream>>>(part, S, chunks);
    k_uuq<<<dim3(144, B), 256, 0, stream>>>(S, Wqkv, U, Uq);
    k_attn<<<dim3(HEADS, B), 256, 0, stream>>>(U, Uq, Wqkv, temp, attn);
    k_mp<<<dim3(8, B), 256, 0, stream>>>(attn, Wout, Wqkv, phi, plo);
    k_out<<<dim3(128, B), 256, 0, stream>>>(x, phi, plo, out);
}